// Round 1
// baseline (297.937 us; speedup 1.0000x reference)
//
#include <hip/hip_runtime.h>
#include <hip/hip_bf16.h>
#include <cmath>

typedef __bf16 bf16_t;
typedef __bf16 bf16x8 __attribute__((ext_vector_type(8)));
typedef __bf16 bf16x4 __attribute__((ext_vector_type(4)));
typedef float  f32x4  __attribute__((ext_vector_type(4)));

static constexpr int B_  = 2, S_ = 2048, H_ = 1024, I_ = 2048, NST = 16;
static constexpr int ROWS  = B_ * S_;      // 4096
static constexpr int TWO_I = 2 * I_;       // 4096
static constexpr int XPD   = 2 * NST + 1;  // 33
static constexpr int XPDP  = 36;           // padded to 16B multiple

#define AS_G(p) ((const __attribute__((address_space(1))) void*)(p))
#define AS_L(p) ((__attribute__((address_space(3))) void*)(p))

// ---------------- prep kernels ----------------

__global__ __launch_bounds__(256) void cvt_bf16_kernel(
    const float* __restrict__ in, bf16_t* __restrict__ out, int n4)
{
    int i = blockIdx.x * 256 + threadIdx.x;
    if (i < n4) {
        f32x4 v = *(const f32x4*)(in + (size_t)i * 4);
        bf16x4 o;
        o[0] = (bf16_t)v[0]; o[1] = (bf16_t)v[1];
        o[2] = (bf16_t)v[2]; o[3] = (bf16_t)v[3];
        *(bf16x4*)(out + (size_t)i * 4) = o;
    }
}

// in: f32 [R][C] -> out: bf16 [C][R]
__global__ __launch_bounds__(256) void tcvt_kernel(
    const float* __restrict__ in, bf16_t* __restrict__ out, int R, int C)
{
    __shared__ float t[32][33];
    const int tx = threadIdx.x, ty = threadIdx.y;
    const int r0 = blockIdx.y * 32, c0 = blockIdx.x * 32;
    #pragma unroll
    for (int k = 0; k < 4; ++k)
        t[ty + 8 * k][tx] = in[(size_t)(r0 + ty + 8 * k) * C + c0 + tx];
    __syncthreads();
    #pragma unroll
    for (int k = 0; k < 4; ++k)
        out[(size_t)(c0 + ty + 8 * k) * R + r0 + tx] = (bf16_t)t[tx][ty + 8 * k];
}

__device__ __forceinline__ float softplus_f(float x) {
    return x > 15.f ? x : log1pf(__expf(x));
}

// A2[i][n] = -clip(softplus(A),0.1,10)*log2(e) ; Wxp = Wx padded [I][36]
__global__ __launch_bounds__(256) void prep_misc_kernel(
    const float* __restrict__ A_param, float* __restrict__ A2,
    const float* __restrict__ Wx, float* __restrict__ Wxp)
{
    int i = blockIdx.x * 256 + threadIdx.x;
    if (i < I_ * NST) {
        float sp = softplus_f(A_param[i]);
        A2[i] = -fminf(fmaxf(sp, 0.1f), 10.f) * 1.44269504088896340736f;
    }
    if (i < I_ * XPDP) {
        int c = i / XPDP, j = i % XPDP;
        Wxp[i] = (j < XPD) ? Wx[(size_t)c * XPD + j] : 0.f;
    }
}

// ---------------- GEMM: C[M][N] = A[M][K] * Bt[N][K]^T  (bf16 in, f32 out) ----------------

template<int M, int N, int K>
__global__ __launch_bounds__(256)
void gemm_bt(const bf16_t* __restrict__ A, const bf16_t* __restrict__ Bt,
             float* __restrict__ C)
{
    constexpr int BM = 128, BN = 128, BK = 32;
    __shared__ bf16_t lA[BM * BK];
    __shared__ bf16_t lB[BN * BK];

    const int bm   = blockIdx.y * BM;
    const int bn   = blockIdx.x * BN;
    const int tid  = threadIdx.x;
    const int lane = tid & 63;
    const int wave = tid >> 6;
    const int wm   = (wave >> 1) * 64;
    const int wn   = (wave & 1) * 64;

    const int srow  = lane >> 2;        // 0..15 (staging row within 16-row chunk)
    const int skoff = (lane & 3) * 8;   // k element offset (16B granules)

    const int frow = lane & 15;         // fragment row/col
    const int fko  = (lane >> 4) * 8;   // fragment k offset

    f32x4 acc[4][4];
    #pragma unroll
    for (int m = 0; m < 4; ++m)
        #pragma unroll
        for (int n = 0; n < 4; ++n)
            acc[m][n] = (f32x4){0.f, 0.f, 0.f, 0.f};

    for (int k0 = 0; k0 < K; k0 += BK) {
        #pragma unroll
        for (int t = 0; t < 2; ++t) {
            const int c = wave * 2 + t; // 0..7 -> 16-row chunk
            const bf16_t* ga = A  + (size_t)(bm + c * 16 + srow) * K + k0 + skoff;
            const bf16_t* gb = Bt + (size_t)(bn + c * 16 + srow) * K + k0 + skoff;
            __builtin_amdgcn_global_load_lds(AS_G(ga), AS_L(lA + c * 512), 16, 0, 0);
            __builtin_amdgcn_global_load_lds(AS_G(gb), AS_L(lB + c * 512), 16, 0, 0);
        }
        __syncthreads();

        bf16x8 af[4], bfr[4];
        #pragma unroll
        for (int m = 0; m < 4; ++m)
            af[m] = *(const bf16x8*)(lA + (wm + m * 16 + frow) * BK + fko);
        #pragma unroll
        for (int n = 0; n < 4; ++n)
            bfr[n] = *(const bf16x8*)(lB + (wn + n * 16 + frow) * BK + fko);

        #pragma unroll
        for (int m = 0; m < 4; ++m)
            #pragma unroll
            for (int n = 0; n < 4; ++n)
                acc[m][n] = __builtin_amdgcn_mfma_f32_16x16x32_bf16(
                    af[m], bfr[n], acc[m][n], 0, 0, 0);

        __syncthreads();
    }

    const int crow = (lane >> 4) * 4;
    const int ccol = lane & 15;
    #pragma unroll
    for (int m = 0; m < 4; ++m)
        #pragma unroll
        for (int n = 0; n < 4; ++n)
            #pragma unroll
            for (int r = 0; r < 4; ++r)
                C[(size_t)(bm + wm + m * 16 + crow + r) * N
                  + (bn + wn + n * 16 + ccol)] = acc[m][n][r];
}

// ---------------- fused middle: conv+silu+LN+xproj+SSM+gate -> U (bf16) ----------------
// one wave per row (b,s); 4 rows per block; lane handles 32 channels (8 x f32x4)

__global__ __launch_bounds__(256)
void fused_mid(const float* __restrict__ xz,      // [ROWS][TWO_I]
               const float* __restrict__ conv_w,  // [I_][4]
               const float* __restrict__ ln_g,
               const float* __restrict__ ln_b,
               const float* __restrict__ Wxp,     // [I_][36]
               const float* __restrict__ A2,      // [I_][16]
               const float* __restrict__ Dv,      // [I_]
               bf16_t* __restrict__ U)            // [ROWS][I_]
{
    const int tid  = threadIdx.x;
    const int lane = tid & 63;
    const int wave = tid >> 6;
    const int row  = blockIdx.x * 4 + wave;
    const int s    = row & (S_ - 1);

    __shared__ float red[4][64 * XPD];
    float* wred = red[wave];

    const float* xzr = xz + (size_t)row * TWO_I;

    float xcn[32];
    float summ = 0.f, ssq = 0.f;

    // conv (causal, K=4) + silu + LN partial sums
    #pragma unroll
    for (int g = 0; g < 8; ++g) {
        const int c = g * 256 + lane * 4;
        const f32x4 w0 = *(const f32x4*)(conv_w + (size_t)(c + 0) * 4);
        const f32x4 w1 = *(const f32x4*)(conv_w + (size_t)(c + 1) * 4);
        const f32x4 w2 = *(const f32x4*)(conv_w + (size_t)(c + 2) * 4);
        const f32x4 w3 = *(const f32x4*)(conv_w + (size_t)(c + 3) * 4);
        f32x4 a = (f32x4){0.f, 0.f, 0.f, 0.f};
        #pragma unroll
        for (int j = 0; j < 4; ++j) {
            if (s + j >= 3) {
                const f32x4 xv = *(const f32x4*)(xzr + (ptrdiff_t)(j - 3) * TWO_I + c);
                const f32x4 wj = (f32x4){w0[j], w1[j], w2[j], w3[j]};
                a += xv * wj;
            }
        }
        #pragma unroll
        for (int e = 0; e < 4; ++e) {
            const float v  = a[e];
            const float sv = v / (1.f + __expf(-v)); // silu
            xcn[g * 4 + e] = sv;
            summ += sv;
            ssq  += sv * sv;
        }
    }

    // wave-level LN reduction
    #pragma unroll
    for (int off = 32; off > 0; off >>= 1) {
        summ += __shfl_xor(summ, off, 64);
        ssq  += __shfl_xor(ssq,  off, 64);
    }
    const float mu = summ * (1.f / I_);
    const float rs = rsqrtf(ssq * (1.f / I_) - mu * mu + 1e-5f);

    // normalize + xproj partial dots
    f32x4 p4[9];
    #pragma unroll
    for (int q = 0; q < 9; ++q) p4[q] = (f32x4){0.f, 0.f, 0.f, 0.f};

    #pragma unroll
    for (int g = 0; g < 8; ++g) {
        const int c = g * 256 + lane * 4;
        const f32x4 gg = *(const f32x4*)(ln_g + c);
        const f32x4 bb = *(const f32x4*)(ln_b + c);
        #pragma unroll
        for (int e = 0; e < 4; ++e) {
            const int i  = g * 4 + e;
            const float xn = (xcn[i] - mu) * rs * gg[e] + bb[e];
            xcn[i] = xn;
            const float* wr = Wxp + (size_t)(c + e) * XPDP;
            #pragma unroll
            for (int q = 0; q < 9; ++q) {
                const f32x4 wv = *(const f32x4*)(wr + q * 4);
                p4[q] += wv * xn;
            }
        }
    }

    // reduce 33 partials across the wave via LDS matrix [64][33] (odd stride: conflict-free)
    #pragma unroll
    for (int j = 0; j < XPD; ++j)
        wred[lane * XPD + j] = p4[j >> 2][j & 3];
    __syncthreads();

    float colsum = 0.f;
    if (lane < XPD) {
        float s0 = 0.f, s1 = 0.f, s2 = 0.f, s3 = 0.f;
        #pragma unroll
        for (int t = 0; t < 64; t += 4) {
            s0 += wred[(t + 0) * XPD + lane];
            s1 += wred[(t + 1) * XPD + lane];
            s2 += wred[(t + 2) * XPD + lane];
            s3 += wred[(t + 3) * XPD + lane];
        }
        colsum = (s0 + s1) + (s2 + s3);
    }
    __syncthreads();
    if (lane < XPD) wred[lane] = colsum;
    __syncthreads();

    // broadcast xp, build delta / B*C
    const float delta = fminf(fmaxf(softplus_f(wred[0]), 1e-6f), 10.f);
    float bc[NST];
    #pragma unroll
    for (int n = 0; n < NST; ++n)
        bc[n] = wred[1 + n] * wred[1 + NST + n];

    // SSM pointwise + gate + store bf16
    const float* zrow = xzr + I_;
    bf16_t* urow = U + (size_t)row * I_;
    #pragma unroll
    for (int g = 0; g < 8; ++g) {
        const int c = g * 256 + lane * 4;
        const f32x4 dv = *(const f32x4*)(Dv + c);
        const f32x4 zv = *(const f32x4*)(zrow + c);
        bf16x4 uo;
        #pragma unroll
        for (int e = 0; e < 4; ++e) {
            const float* a2r = A2 + (size_t)(c + e) * NST;
            f32x4 sacc = (f32x4){0.f, 0.f, 0.f, 0.f};
            #pragma unroll
            for (int q = 0; q < 4; ++q) {
                const f32x4 a4 = *(const f32x4*)(a2r + q * 4);
                #pragma unroll
                for (int t2 = 0; t2 < 4; ++t2)
                    sacc[t2] += bc[q * 4 + t2] * fmaxf(exp2f(delta * a4[t2]), 1e-6f);
            }
            const float ssum = (sacc[0] + sacc[1]) + (sacc[2] + sacc[3]);
            const float y = xcn[g * 4 + e] * (ssum + dv[e]);
            const float z = zv[e];
            uo[e] = (bf16_t)(y * (z / (1.f + __expf(-z))));
        }
        *(bf16x4*)(urow + c) = uo;
    }
}

// ---------------- launch ----------------

extern "C" void kernel_launch(void* const* d_in, const int* in_sizes, int n_in,
                              void* d_out, int out_size, void* d_ws, size_t ws_size,
                              hipStream_t stream)
{
    const float* x     = (const float*)d_in[0];
    const float* W_in  = (const float*)d_in[1];
    const float* convw = (const float*)d_in[2];
    const float* ln_g  = (const float*)d_in[3];
    const float* ln_b  = (const float*)d_in[4];
    const float* Wx    = (const float*)d_in[5];
    const float* A_p   = (const float*)d_in[6];
    const float* Dv    = (const float*)d_in[7];
    const float* W_out = (const float*)d_in[8];
    float* out = (float*)d_out;

    char* ws = (char*)d_ws;
    bf16_t* Xb  = (bf16_t*)(ws);                          // 8 MiB  [4096][1024]
    bf16_t* W1t = (bf16_t*)(ws + (size_t)(8u  << 20));    // 8 MiB  [4096][1024]
    bf16_t* Wot = (bf16_t*)(ws + (size_t)(16u << 20));    // 4 MiB  [1024][2048]
    float*  A2  = (float*) (ws + (size_t)(20u << 20));    // 128 KiB
    float*  Wxp = (float*) (ws + (size_t)(21u << 20));    // 288 KiB
    float*  xz  = (float*) (ws + (size_t)(22u << 20));    // 64 MiB [4096][4096]
    bf16_t* U   = (bf16_t*)(ws + (size_t)(86u << 20));    // 16 MiB [4096][2048]

    cvt_bf16_kernel<<<(ROWS * H_ / 4 + 255) / 256, 256, 0, stream>>>(x, Xb, ROWS * H_ / 4);
    tcvt_kernel<<<dim3(TWO_I / 32, H_ / 32), dim3(32, 8), 0, stream>>>(W_in, W1t, H_, TWO_I);
    tcvt_kernel<<<dim3(H_ / 32, I_ / 32), dim3(32, 8), 0, stream>>>(W_out, Wot, I_, H_);
    prep_misc_kernel<<<(I_ * XPDP + 255) / 256, 256, 0, stream>>>(A_p, A2, Wx, Wxp);

    gemm_bt<ROWS, TWO_I, H_><<<dim3(TWO_I / 128, ROWS / 128), 256, 0, stream>>>(Xb, W1t, xz);
    fused_mid<<<ROWS / 4, 256, 0, stream>>>(xz, convw, ln_g, ln_b, Wxp, A2, Dv, U);
    gemm_bt<ROWS, H_, I_><<<dim3(H_ / 128, ROWS / 128), 256, 0, stream>>>(U, Wot, out);
}